// Round 4
// baseline (659.270 us; speedup 1.0000x reference)
//
#include <hip/hip_runtime.h>

#define DBITS 18

// LDS physical swizzle: XOR-linear, invertible, and for every round below the
// 4 within-16-lane-group varying j-bits map to linearly independent low-4 images.
__device__ __forceinline__ int physf(int j){ return j ^ ((j>>4)&15) ^ ((j>>8)&15); }

template<int b0,int b1,int b2,int b3>
__device__ __forceinline__ constexpr int dep4(int c){
  return ((c&1)<<b0) | (((c>>1)&1)<<b1) | (((c>>2)&1)<<b2) | (((c>>3)&1)<<b3);
}
template<int b0,int b1,int b2,int b3>
__device__ __forceinline__ constexpr int pdep4(int c){
  const int d = dep4<b0,b1,b2,b3>(c);
  return d ^ ((d>>4)&15) ^ ((d>>8)&15);
}

__device__ __forceinline__ unsigned pack_bf2(float r, float i){
  unsigned ur = __float_as_uint(r), ui = __float_as_uint(i);
  ur = (ur + 0x7FFFu + ((ur >> 16) & 1u)) >> 16;
  ui = (ui + 0x7FFFu + ((ui >> 16) & 1u)) & 0xFFFF0000u;
  return ur | ui;
}
__device__ __forceinline__ float2 unpack_bf2(unsigned u){
  return make_float2(__uint_as_float(u << 16), __uint_as_float(u & 0xFFFF0000u));
}

// SU(2) gate U = [[a,b],[-conj(b),conj(a)]], g = {ar,ai,br,bi}.
template<int S>
__device__ __forceinline__ void gate_reg(float ar[16], float ai[16], const float* __restrict__ g){
  const float Ar=g[0], Ai=g[1], Br=g[2], Bi=g[3];
  #pragma unroll
  for (int h = 0; h < 8; ++h){
    const int c0 = ((h & ~(S-1)) << 1) | (h & (S-1));
    const int c1 = c0 | S;
    const float x0r=ar[c0], x0i=ai[c0], x1r=ar[c1], x1i=ai[c1];
    ar[c0] =  Ar*x0r - Ai*x0i + Br*x1r - Bi*x1i;
    ai[c0] =  Ar*x0i + Ai*x0r + Br*x1i + Bi*x1r;
    ar[c1] = -Br*x0r - Bi*x0i + Ar*x1r + Ai*x1i;
    ai[c1] = -Br*x0i + Bi*x0r + Ar*x1i - Ai*x1r;
  }
}

template<int CTRL>
__device__ __forceinline__ float dppf(float v){
  return __int_as_float(__builtin_amdgcn_update_dpp(0, __float_as_int(v), CTRL, 0xF, 0xF, true));
}
// Gate on a lane bit (xor1: 0xB1 <-> t0, xor2: 0x4E <-> t1). s=-1 when the bit is set.
template<int CTRL>
__device__ __forceinline__ void gate_lane(float ar[16], float ai[16], const float* __restrict__ g, float s){
  const float uer = g[0], uei = s*g[1], uor = s*g[2], uoi = g[3];
  #pragma unroll
  for (int c = 0; c < 16; ++c){
    const float pr = dppf<CTRL>(ar[c]);
    const float pi = dppf<CTRL>(ai[c]);
    const float xr = ar[c], xi = ai[c];
    ar[c] = uer*xr - uei*xi + uor*pr - uoi*pi;
    ai[c] = uer*xi + uei*xr + uor*pi + uoi*pr;
  }
}

__device__ __forceinline__ const float* gp(const float* __restrict__ gates, int L, int ggbit){
  return gates + (L*18 + (17 - ggbit))*4;
}

// ===== Gate ledger (verified, each (layer, gg-bit) exactly once) =====
// P1 (SL=13, j==gg[0..12]):  L1: R1 reg b0-3 + dpp b4,b5 | R2 reg b6-9 | R3 reg b10-12
// P2 (SL=8, j0-7=gg0-7, j8-12=gg13-17):
//   R1 reg L1 b13,b14,b15,b17 | R2: L1 b16, sign1, L2 b16,b0,b1,b2 + dpp L2 b3,b4
//   R3: L2 b5,b6,b7,b13 + dpp L2 b14,b15
// P3 (SL=3, j0-2=gg0-2, j3-12=gg8-17):
//   R1: L2 b8,b11,b12,b17 + dpp L2 b9,b10 -> sign2 -> L3 b8,b11,b12,b17 + dpp L3 b9,b10
//   R2: L3 b13,b14,b15,b16 + dpp L3 b0,b1 | R3: store only
// P4 (SL=13): R1: L3 b2,b3 + dpp L3 b4,b5 | R2: L3 b6,b7 + head reduce
// sign1 in P2R2 (L1 complete), sign2 in P3R1 (L2 complete), final CZ absorbed by |amp|^2.
template<int PASS>
__global__ __launch_bounds__(512, 4)
void qpass(const float* __restrict__ sr, const float* __restrict__ si,
           unsigned* __restrict__ st, const float* __restrict__ gates,
           const float* __restrict__ head_w, float* __restrict__ partials,
           int batch0)
{
  __shared__ float2 lds[8192];
  const int t = threadIdx.x;
  const int f  = (int)blockIdx.x & 31;
  const int bl = (int)blockIdx.x >> 5;
  const int bg = batch0 + bl;
  const unsigned stBase = ((unsigned)bl) << DBITS;
  const size_t  inBase  = ((size_t)bg) << DBITS;
  const float s1 = (t & 1) ? -1.f : 1.f;
  const float s2 = (t & 2) ? -1.f : 1.f;

  float ar[16], ai[16];

  if (PASS == 1){
    // ---- R1: c=j[0..3], vec4 input load ----
    {
      const size_t base = inBase + ((size_t)f << 13) + ((size_t)t << 4);
      const float4* r4 = reinterpret_cast<const float4*>(sr + base);
      const float4* i4 = reinterpret_cast<const float4*>(si + base);
      #pragma unroll
      for (int q = 0; q < 4; ++q){
        const float4 vr = r4[q], vi = i4[q];
        ar[4*q+0]=vr.x; ar[4*q+1]=vr.y; ar[4*q+2]=vr.z; ar[4*q+3]=vr.w;
        ai[4*q+0]=vi.x; ai[4*q+1]=vi.y; ai[4*q+2]=vi.z; ai[4*q+3]=vi.w;
      }
      gate_reg<1>(ar,ai, gp(gates,0,0));
      gate_reg<2>(ar,ai, gp(gates,0,1));
      gate_reg<4>(ar,ai, gp(gates,0,2));
      gate_reg<8>(ar,ai, gp(gates,0,3));
      gate_lane<0xB1>(ar,ai, gp(gates,0,4), s1);
      gate_lane<0x4E>(ar,ai, gp(gates,0,5), s2);
      const int pj = physf(t << 4);
      #pragma unroll
      for (int c = 0; c < 16; ++c) lds[pj ^ pdep4<0,1,2,3>(c)] = make_float2(ar[c], ai[c]);
    }
    __syncthreads();
    // ---- R2: c=j[6..9] ----
    {
      const int jb = (t & 63) | (((t >> 6) & 7) << 10);
      const int pj = physf(jb);
      #pragma unroll
      for (int c = 0; c < 16; ++c){ const float2 v = lds[pj ^ pdep4<6,7,8,9>(c)]; ar[c]=v.x; ai[c]=v.y; }
      gate_reg<1>(ar,ai, gp(gates,0,6));
      gate_reg<2>(ar,ai, gp(gates,0,7));
      gate_reg<4>(ar,ai, gp(gates,0,8));
      gate_reg<8>(ar,ai, gp(gates,0,9));
      #pragma unroll
      for (int c = 0; c < 16; ++c) lds[pj ^ pdep4<6,7,8,9>(c)] = make_float2(ar[c], ai[c]);
    }
    __syncthreads();
    // ---- R3: c=j[9..12], gates j10-12, store ----
    {
      const int jb = t;  // j[0..8]
      const int pj = physf(jb);
      #pragma unroll
      for (int c = 0; c < 16; ++c){ const float2 v = lds[pj ^ pdep4<9,10,11,12>(c)]; ar[c]=v.x; ai[c]=v.y; }
      gate_reg<2>(ar,ai, gp(gates,0,10));
      gate_reg<4>(ar,ai, gp(gates,0,11));
      gate_reg<8>(ar,ai, gp(gates,0,12));
      const unsigned base = stBase + ((unsigned)f << 13) + (unsigned)t;
      #pragma unroll
      for (int c = 0; c < 16; ++c) st[base + ((unsigned)c << 9)] = pack_bf2(ar[c], ai[c]);
    }
  }
  else if (PASS == 2){
    // ---- R1: c={j8,j9,j10,j12} -> gg{13,14,15,17} ----
    {
      const int jb = (t & 255) | (((t >> 8) & 1) << 11);
      const unsigned ggb = (unsigned)((t & 255) | (((t >> 8) & 1) << 16) | (f << 8));
      #pragma unroll
      for (int c = 0; c < 16; ++c){
        const unsigned gg = ggb + (unsigned)(((c&1)<<13) | (((c>>1)&1)<<14) | (((c>>2)&1)<<15) | (((c>>3)&1)<<17));
        const float2 v = unpack_bf2(st[stBase + gg]); ar[c]=v.x; ai[c]=v.y;
      }
      gate_reg<1>(ar,ai, gp(gates,0,13));
      gate_reg<2>(ar,ai, gp(gates,0,14));
      gate_reg<4>(ar,ai, gp(gates,0,15));
      gate_reg<8>(ar,ai, gp(gates,0,17));
      const int pj = physf(jb);
      #pragma unroll
      for (int c = 0; c < 16; ++c) lds[pj ^ pdep4<8,9,10,12>(c)] = make_float2(ar[c], ai[c]);
    }
    __syncthreads();
    // ---- R2: c={j11,j0,j1,j2}: L1 b16, sign1, L2 b16,b0,b1,b2 + dpp L2 b3,b4 ----
    {
      const int jb = ((t & 31) << 3) | (((t >> 5) & 7) << 8) | (((t >> 8) & 1) << 12);
      const int pj = physf(jb);
      #pragma unroll
      for (int c = 0; c < 16; ++c){ const float2 v = lds[pj ^ pdep4<11,0,1,2>(c)]; ar[c]=v.x; ai[c]=v.y; }
      gate_reg<1>(ar,ai, gp(gates,0,16));             // last L1
      const unsigned ggb = (unsigned)(((jb >> 8) << 13) | (f << 8) | (jb & 255));
      #pragma unroll
      for (int c = 0; c < 16; ++c){                   // sign1
        const unsigned gg = ggb + (unsigned)(((c&1)<<16) | ((c>>1)&1) | (((c>>2)&1)<<1) | (((c>>3)&1)<<2));
        const unsigned sb = (unsigned)(__popc(gg & (gg >> 1)) & 1) << 31;
        ar[c] = __uint_as_float(__float_as_uint(ar[c]) ^ sb);
        ai[c] = __uint_as_float(__float_as_uint(ai[c]) ^ sb);
      }
      gate_reg<1>(ar,ai, gp(gates,1,16));
      gate_reg<2>(ar,ai, gp(gates,1,0));
      gate_reg<4>(ar,ai, gp(gates,1,1));
      gate_reg<8>(ar,ai, gp(gates,1,2));
      gate_lane<0xB1>(ar,ai, gp(gates,1,3), s1);
      gate_lane<0x4E>(ar,ai, gp(gates,1,4), s2);
      #pragma unroll
      for (int c = 0; c < 16; ++c) lds[pj ^ pdep4<11,0,1,2>(c)] = make_float2(ar[c], ai[c]);
    }
    __syncthreads();
    // ---- R3: c={j5,j6,j7,j8}: L2 b5,b6,b7,b13 + dpp L2 b14,b15; store ----
    {
      const int jb = ((t&1)<<9) | (((t>>1)&1)<<10) | (((t>>2)&1)<<0) | (((t>>3)&1)<<3)
                   | (((t>>4)&1)<<1) | (((t>>5)&1)<<2) | (((t>>6)&1)<<4)
                   | (((t>>7)&1)<<11) | (((t>>8)&1)<<12);
      const int pj = physf(jb);
      #pragma unroll
      for (int c = 0; c < 16; ++c){ const float2 v = lds[pj ^ pdep4<5,6,7,8>(c)]; ar[c]=v.x; ai[c]=v.y; }
      gate_reg<1>(ar,ai, gp(gates,1,5));
      gate_reg<2>(ar,ai, gp(gates,1,6));
      gate_reg<4>(ar,ai, gp(gates,1,7));
      gate_reg<8>(ar,ai, gp(gates,1,13));
      gate_lane<0xB1>(ar,ai, gp(gates,1,14), s1);
      gate_lane<0x4E>(ar,ai, gp(gates,1,15), s2);
      const unsigned ggb = (unsigned)(((jb >> 8) << 13) | (f << 8) | (jb & 255));
      #pragma unroll
      for (int c = 0; c < 16; ++c){
        const unsigned gg = ggb + (unsigned)(((c&1)<<5) | (((c>>1)&1)<<6) | (((c>>2)&1)<<7) | (((c>>3)&1)<<13));
        st[stBase + gg] = pack_bf2(ar[c], ai[c]);
      }
    }
  }
  else if (PASS == 3){
    // ---- R1: c={j3,j6,j7,j12} -> gg{8,11,12,17}: L2 finish, sign2, L3 ----
    {
      const int jb = ((t&1)<<4) | (((t>>1)&1)<<5) | (((t>>2)&1)<<2) | (((t>>3)&1)<<11)
                   | (((t>>4)&1)<<0) | (((t>>5)&1)<<1) | (((t>>6)&1)<<8)
                   | (((t>>7)&1)<<9) | (((t>>8)&1)<<10);
      const unsigned ggb = (unsigned)(((jb >> 3) << 8) | (f << 3) | (jb & 7));
      #pragma unroll
      for (int c = 0; c < 16; ++c){
        const unsigned gg = ggb + (unsigned)(((c&1)<<8) | (((c>>1)&1)<<11) | (((c>>2)&1)<<12) | (((c>>3)&1)<<17));
        const float2 v = unpack_bf2(st[stBase + gg]); ar[c]=v.x; ai[c]=v.y;
      }
      gate_reg<1>(ar,ai, gp(gates,1,8));
      gate_reg<2>(ar,ai, gp(gates,1,11));
      gate_reg<4>(ar,ai, gp(gates,1,12));
      gate_reg<8>(ar,ai, gp(gates,1,17));
      gate_lane<0xB1>(ar,ai, gp(gates,1,9),  s1);
      gate_lane<0x4E>(ar,ai, gp(gates,1,10), s2);   // L2 complete
      #pragma unroll
      for (int c = 0; c < 16; ++c){                 // sign2
        const unsigned gg = ggb + (unsigned)(((c&1)<<8) | (((c>>1)&1)<<11) | (((c>>2)&1)<<12) | (((c>>3)&1)<<17));
        const unsigned sb = (unsigned)(__popc(gg & (gg >> 1)) & 1) << 31;
        ar[c] = __uint_as_float(__float_as_uint(ar[c]) ^ sb);
        ai[c] = __uint_as_float(__float_as_uint(ai[c]) ^ sb);
      }
      gate_reg<1>(ar,ai, gp(gates,2,8));
      gate_reg<2>(ar,ai, gp(gates,2,11));
      gate_reg<4>(ar,ai, gp(gates,2,12));
      gate_reg<8>(ar,ai, gp(gates,2,17));
      gate_lane<0xB1>(ar,ai, gp(gates,2,9),  s1);
      gate_lane<0x4E>(ar,ai, gp(gates,2,10), s2);
      const int pj = physf(jb);
      #pragma unroll
      for (int c = 0; c < 16; ++c) lds[pj ^ pdep4<3,6,7,12>(c)] = make_float2(ar[c], ai[c]);
    }
    __syncthreads();
    // ---- R2: c=j[8..11]: L3 b13-16 + dpp L3 b0,b1 ----
    {
      const int jb = (t & 255) | (((t >> 8) & 1) << 12);
      const int pj = physf(jb);
      #pragma unroll
      for (int c = 0; c < 16; ++c){ const float2 v = lds[pj ^ pdep4<8,9,10,11>(c)]; ar[c]=v.x; ai[c]=v.y; }
      gate_reg<1>(ar,ai, gp(gates,2,13));
      gate_reg<2>(ar,ai, gp(gates,2,14));
      gate_reg<4>(ar,ai, gp(gates,2,15));
      gate_reg<8>(ar,ai, gp(gates,2,16));
      gate_lane<0xB1>(ar,ai, gp(gates,2,0), s1);
      gate_lane<0x4E>(ar,ai, gp(gates,2,1), s2);
      #pragma unroll
      for (int c = 0; c < 16; ++c) lds[pj ^ pdep4<8,9,10,11>(c)] = make_float2(ar[c], ai[c]);
    }
    __syncthreads();
    // ---- R3: c=j[0..3], no gates, uint4 store ----
    {
      const int pj = physf(t << 4);
      unsigned u[16];
      #pragma unroll
      for (int c = 0; c < 16; ++c){
        const float2 v = lds[pj ^ pdep4<0,1,2,3>(c)];
        u[c] = pack_bf2(v.x, v.y);
      }
      const unsigned base = stBase + ((unsigned)t << 9) + ((unsigned)f << 3);
      *reinterpret_cast<uint4*>(st + base)           = make_uint4(u[0],u[1],u[2],u[3]);
      *reinterpret_cast<uint4*>(st + base + 4)       = make_uint4(u[4],u[5],u[6],u[7]);
      *reinterpret_cast<uint4*>(st + base + 256)     = make_uint4(u[8],u[9],u[10],u[11]);
      *reinterpret_cast<uint4*>(st + base + 260)     = make_uint4(u[12],u[13],u[14],u[15]);
    }
  }
  else {
    // ---- P4 R1: c=j[0..3], uint4 load: L3 b2,b3 + dpp L3 b4,b5 ----
    {
      const unsigned base = stBase + ((unsigned)f << 13) + ((unsigned)t << 4);
      const uint4* s4 = reinterpret_cast<const uint4*>(st + base);
      #pragma unroll
      for (int q = 0; q < 4; ++q){
        const uint4 uu = s4[q];
        float2 v;
        v = unpack_bf2(uu.x); ar[4*q+0]=v.x; ai[4*q+0]=v.y;
        v = unpack_bf2(uu.y); ar[4*q+1]=v.x; ai[4*q+1]=v.y;
        v = unpack_bf2(uu.z); ar[4*q+2]=v.x; ai[4*q+2]=v.y;
        v = unpack_bf2(uu.w); ar[4*q+3]=v.x; ai[4*q+3]=v.y;
      }
      gate_reg<4>(ar,ai, gp(gates,2,2));
      gate_reg<8>(ar,ai, gp(gates,2,3));
      gate_lane<0xB1>(ar,ai, gp(gates,2,4), s1);
      gate_lane<0x4E>(ar,ai, gp(gates,2,5), s2);
      const int pj = physf(t << 4);
      #pragma unroll
      for (int c = 0; c < 16; ++c) lds[pj ^ pdep4<0,1,2,3>(c)] = make_float2(ar[c], ai[c]);
    }
    __syncthreads();
    // ---- P4 R2: c=j[6..9]: L3 b6,b7 + fused head ----
    {
      const int jb = (t & 63) | (((t >> 6) & 7) << 10);
      const int pj = physf(jb);
      #pragma unroll
      for (int c = 0; c < 16; ++c){ const float2 v = lds[pj ^ pdep4<6,7,8,9>(c)]; ar[c]=v.x; ai[c]=v.y; }
      gate_reg<1>(ar,ai, gp(gates,2,6));
      gate_reg<2>(ar,ai, gp(gates,2,7));
      const int gg0 = (f << 13) | jb;
      float cb = 0.f;
      #pragma unroll
      for (int k = 0; k < 18; ++k){
        const float hw = head_w[17 - k];
        cb += ((gg0 >> k) & 1) ? -hw : hw;
      }
      // c bits -> gg{6,7,8,9} -> wires {11,10,9,8}
      const float d0 = -2.f*head_w[11], d1 = -2.f*head_w[10];
      const float d2 = -2.f*head_w[9],  d3 = -2.f*head_w[8];
      float acc = 0.f;
      #pragma unroll
      for (int c = 0; c < 16; ++c){
        float coef = cb;
        if (c & 1) coef += d0;
        if (c & 2) coef += d1;
        if (c & 4) coef += d2;
        if (c & 8) coef += d3;
        acc += coef * (ar[c]*ar[c] + ai[c]*ai[c]);
      }
      __syncthreads();   // all LDS reads done; reuse LDS for reduction
      #pragma unroll
      for (int off = 32; off; off >>= 1) acc += __shfl_down(acc, off);
      float* red = reinterpret_cast<float*>(lds);
      if ((t & 63) == 0) red[t >> 6] = acc;
      __syncthreads();
      if (t == 0){
        float s = 0.f;
        #pragma unroll
        for (int i = 0; i < 8; ++i) s += red[i];
        partials[bg * 32 + f] = s;
      }
    }
  }
}

__global__ void qprep(const float* __restrict__ params, float* __restrict__ gates){
  const int tid = threadIdx.x;
  if (tid < 54){
    const float xx = params[tid*3+0]*0.5f, yy = params[tid*3+1]*0.5f, zz = params[tid*3+2]*0.5f;
    float sx,cx,sy,cy,sz,cz;
    sincosf(xx,&sx,&cx); sincosf(yy,&sy,&cy); sincosf(zz,&sz,&cz);
    float* gp = gates + tid*4;
    gp[0] =  cz*cy*cx + sz*sy*sx;   // a_r (u00)
    gp[1] =  cz*sy*sx - sz*cy*cx;   // a_i
    gp[2] = -cz*sy*cx - sz*cy*sx;   // b_r (u01)
    gp[3] =  sz*sy*cx - cz*cy*sx;   // b_i
  }
}

__global__ void qfinal(const float* __restrict__ partials, const float* __restrict__ head_b,
                       float* __restrict__ out, int B){
  const int b = threadIdx.x + blockIdx.x * blockDim.x;
  if (b < B){
    float s = head_b[0];
    #pragma unroll
    for (int i = 0; i < 32; ++i) s += partials[b*32 + i];
    out[b] = s;
  }
}

extern "C" void kernel_launch(void* const* d_in, const int* in_sizes, int n_in,
                              void* d_out, int out_size, void* d_ws, size_t ws_size,
                              hipStream_t stream){
  const float* sr     = (const float*)d_in[0];
  const float* si     = (const float*)d_in[1];
  const float* params = (const float*)d_in[2];
  const float* head_w = (const float*)d_in[3];
  const float* head_b = (const float*)d_in[4];
  float* out = (float*)d_out;
  const int B = in_sizes[0] >> DBITS;   // 128

  float*    gates    = (float*)d_ws;                        // 54*4 floats
  float*    partials = (float*)((char*)d_ws + 4096);        // B*32 floats (16 KiB)
  unsigned* st       = (unsigned*)((char*)d_ws + 24576);    // bf16-packed state chunk

  size_t stBytes = ws_size > 24576 ? ws_size - 24576 : 0;
  int maxChunk = (int)(stBytes / ((size_t)(1 << DBITS) * 4));
  if (maxChunk > B) maxChunk = B;
  if (maxChunk < 1) maxChunk = 1;

  qprep<<<dim3(1), dim3(64), 0, stream>>>(params, gates);

  for (int b0 = 0; b0 < B; b0 += maxChunk){
    const int c = (B - b0 < maxChunk) ? (B - b0) : maxChunk;
    dim3 grid(c * 32), blk(512);
    qpass<1><<<grid, blk, 0, stream>>>(sr, si, st, gates, head_w, partials, b0);
    qpass<2><<<grid, blk, 0, stream>>>(sr, si, st, gates, head_w, partials, b0);
    qpass<3><<<grid, blk, 0, stream>>>(sr, si, st, gates, head_w, partials, b0);
    qpass<4><<<grid, blk, 0, stream>>>(sr, si, st, gates, head_w, partials, b0);
  }
  qfinal<<<dim3(1), dim3(128), 0, stream>>>(partials, head_b, out, B);
}

// Round 5
// 395.270 us; speedup vs baseline: 1.6679x; 1.6679x over previous
//
#include <hip/hip_runtime.h>

#define DBITS 18

typedef float v2f __attribute__((ext_vector_type(2)));

// LDS physical swizzle (XOR-linear). Low-4 images: j0-3->e0-3, j4-7->e0-3,
// j8-11->e0-3, j12->e0. Every round's t0..t3 j-bits map to independent images.
__device__ __forceinline__ int physx(int j){ return j ^ ((j>>4)&15) ^ ((j>>8)&15) ^ ((j>>12)&1); }

template<int b0,int b1,int b2,int b3>
__device__ __forceinline__ int dep4(int c){
  return ((c&1)<<b0) | (((c>>1)&1)<<b1) | (((c>>2)&1)<<b2) | (((c>>3)&1)<<b3);
}
template<int b0,int b1,int b2,int b3>
__device__ __forceinline__ int pdep4(int c){
  const int d = dep4<b0,b1,b2,b3>(c);
  return d ^ ((d>>4)&15) ^ ((d>>8)&15) ^ ((d>>12)&1);
}

__device__ __forceinline__ unsigned pack_bf2(v2f v){
  unsigned ur = __float_as_uint(v.x), ui = __float_as_uint(v.y);
  ur = (ur + 0x7FFFu + ((ur >> 16) & 1u)) >> 16;
  ui = (ui + 0x7FFFu + ((ui >> 16) & 1u)) & 0xFFFF0000u;
  return ur | ui;
}
__device__ __forceinline__ v2f unpack_bf2(unsigned u){
  v2f v; v.x = __uint_as_float(u << 16); v.y = __uint_as_float(u & 0xFFFF0000u); return v;
}

// ---- packed f32 complex helpers (v_pk_fma_f32 with op_sel swap tricks) ----
__device__ __forceinline__ v2f pk_mul(v2f x, v2f s){
  v2f r; asm("v_pk_mul_f32 %0, %1, %2" : "=v"(r) : "v"(x), "v"(s)); return r;
}
__device__ __forceinline__ v2f pk_mul_neg(v2f x, v2f s){
  v2f r; asm("v_pk_mul_f32 %0, %1, %2 neg_lo:[1,0] neg_hi:[1,0]" : "=v"(r) : "v"(x), "v"(s)); return r;
}
__device__ __forceinline__ v2f pk_fma(v2f x, v2f s, v2f a){
  v2f r; asm("v_pk_fma_f32 %0, %1, %2, %3" : "=v"(r) : "v"(x), "v"(s), "v"(a)); return r;
}
// r = s * (-x.hi, x.lo) + a
__device__ __forceinline__ v2f pk_fma_swlo(v2f x, v2f s, v2f a){
  v2f r; asm("v_pk_fma_f32 %0, %1, %2, %3 op_sel:[1,0,0] op_sel_hi:[0,1,1] neg_lo:[1,0,0]"
             : "=v"(r) : "v"(x), "v"(s), "v"(a)); return r;
}
// r = s * (x.hi, -x.lo) + a
__device__ __forceinline__ v2f pk_fma_swhi(v2f x, v2f s, v2f a){
  v2f r; asm("v_pk_fma_f32 %0, %1, %2, %3 op_sel:[1,0,0] op_sel_hi:[0,1,1] neg_hi:[1,0,0]"
             : "=v"(r) : "v"(x), "v"(s), "v"(a)); return r;
}

// SU(2) gate U=[[a,b],[-conj(b),conj(a)]], g={Ar,Ai,Br,Bi}; amps as (re,im) pairs.
template<int S>
__device__ __forceinline__ void gate_pk(v2f a[16], const float* __restrict__ g){
  const v2f Ar = {g[0],g[0]}, Ai = {g[1],g[1]}, Br = {g[2],g[2]}, Bi = {g[3],g[3]};
  #pragma unroll
  for (int h = 0; h < 8; ++h){
    const int c0 = ((h & ~(S-1)) << 1) | (h & (S-1));
    const int c1 = c0 | S;
    const v2f X0 = a[c0], X1 = a[c1];
    v2f y0 = pk_mul(X0, Ar);
    y0 = pk_fma_swlo(X0, Ai, y0);
    y0 = pk_fma(X1, Br, y0);
    y0 = pk_fma_swlo(X1, Bi, y0);
    v2f y1 = pk_mul_neg(X0, Br);
    y1 = pk_fma_swlo(X0, Bi, y1);
    y1 = pk_fma(X1, Ar, y1);
    y1 = pk_fma_swhi(X1, Ai, y1);
    a[c0] = y0; a[c1] = y1;
  }
}

template<int CTRL>
__device__ __forceinline__ float dppf(float v){
  return __int_as_float(__builtin_amdgcn_update_dpp(0, __float_as_int(v), CTRL, 0xF, 0xF, true));
}
// Gate on lane bit t0 (CTRL=0xB1) or t1 (CTRL=0x4E); s=-1 when the lane's bit is set.
template<int CTRL>
__device__ __forceinline__ void gate_lane_pk(v2f a[16], const float* __restrict__ g, float s){
  const float uei = s*g[1], uor = s*g[2];
  const v2f UER = {g[0],g[0]}, UEI = {uei,uei}, UOR = {uor,uor}, UOI = {g[3],g[3]};
  #pragma unroll
  for (int c = 0; c < 16; ++c){
    const v2f X = a[c];
    v2f P; P.x = dppf<CTRL>(X.x); P.y = dppf<CTRL>(X.y);
    v2f y = pk_mul(X, UER);
    y = pk_fma_swlo(X, UEI, y);
    y = pk_fma(P, UOR, y);
    y = pk_fma_swlo(P, UOI, y);
    a[c] = y;
  }
}

__device__ __forceinline__ const float* gp(const float* __restrict__ gates, int L, int ggbit){
  return gates + (L*18 + (17 - ggbit))*4;
}
__device__ __forceinline__ void sgn(v2f& v, unsigned gg){
  const unsigned sb = (unsigned)(__popc(gg & (gg >> 1)) & 1) << 31;
  v.x = __uint_as_float(__float_as_uint(v.x) ^ sb);
  v.y = __uint_as_float(__float_as_uint(v.y) ^ sb);
}

// ===== Gate ledger (each (layer, gg-bit) exactly once; windows all contain gg0-5) =====
// W1=[0..12] f->13..17 | W2=[0-7,13-17] f->8..12 | W3=[0-5,8-13,17] f->{6,7,14,15,16}
// W4=[0-9,14-16] f->{10,11,12,13,17}
// L1: P1R1 c gg9-12 + dpp gg0,1 | P1R2 c gg2-5 + dpp gg6,7 | P1R3 c gg8 | P2R1 c gg14-17 | P2R2 gg13
// sign1: P2R2 (L1 complete)
// L2: P2R2 c gg13,2,3,4 + dpp gg15,16 | P2R3 c gg6,7,14,17 + dpp gg0,1 | P3R1 c gg11,12 | P3R2 c gg5,8,9,10
// sign2: P3R2 (L2 complete)
// L3: P3R2 c gg5,8,9,10 + dpp gg13,17 | P3R3 c gg11,12 + dpp gg0,1 | P4R1 c gg14,15,16 | P4R2 c gg2,3,4,6 + dpp gg7
// final CZ absorbed by |amp|^2.
template<int PASS>
__global__ __launch_bounds__(512, 4)
void qpass(const float* __restrict__ sr, const float* __restrict__ si,
           unsigned* __restrict__ st, const float* __restrict__ gates,
           const float* __restrict__ head_w, float* __restrict__ partials,
           int batch0)
{
  __shared__ v2f lds[8192];
  const int t = threadIdx.x;
  const int f  = (int)blockIdx.x & 31;
  const int bl = (int)blockIdx.x >> 5;
  const int bg = batch0 + bl;
  const unsigned stBase = ((unsigned)bl) << DBITS;
  const size_t  inBase  = ((size_t)bg) << DBITS;
  const float s1 = (t & 1) ? -1.f : 1.f;
  const float s2 = (t & 2) ? -1.f : 1.f;

  v2f a[16];

  if (PASS == 1){
    // ---- R1: load (t->gg0-8, c->gg9-12), gates gg9-12 + dpp gg0,1 ----
    {
      const size_t base = inBase + ((size_t)f << 13) + (size_t)t;
      #pragma unroll
      for (int c = 0; c < 16; ++c){
        const size_t g = base + ((size_t)c << 9);
        a[c].x = sr[g]; a[c].y = si[g];
      }
      gate_pk<1>(a, gp(gates,0,9));
      gate_pk<2>(a, gp(gates,0,10));
      gate_pk<4>(a, gp(gates,0,11));
      gate_pk<8>(a, gp(gates,0,12));
      gate_lane_pk<0xB1>(a, gp(gates,0,0), s1);
      gate_lane_pk<0x4E>(a, gp(gates,0,1), s2);
      const int pj = physx(t);
      #pragma unroll
      for (int c = 0; c < 16; ++c) lds[pj ^ pdep4<9,10,11,12>(c)] = a[c];
    }
    __syncthreads();
    // ---- R2: c->j2-5, t0,t1->j6,j7; gates gg2-5 + dpp gg6,7 ----
    {
      const int jb = ((t&1)<<6)|(((t>>1)&1)<<7)|(((t>>2)&1)<<0)|(((t>>3)&1)<<1)|((t>>4)<<8);
      const int pj = physx(jb);
      #pragma unroll
      for (int c = 0; c < 16; ++c) a[c] = lds[pj ^ pdep4<2,3,4,5>(c)];
      gate_pk<1>(a, gp(gates,0,2));
      gate_pk<2>(a, gp(gates,0,3));
      gate_pk<4>(a, gp(gates,0,4));
      gate_pk<8>(a, gp(gates,0,5));
      gate_lane_pk<0xB1>(a, gp(gates,0,6), s1);
      gate_lane_pk<0x4E>(a, gp(gates,0,7), s2);
      #pragma unroll
      for (int c = 0; c < 16; ++c) lds[pj ^ pdep4<2,3,4,5>(c)] = a[c];
    }
    __syncthreads();
    // ---- R3: t0-5->j0-5, c->j8-11; gate gg8; store ----
    {
      const int jb = (t&63)|(((t>>6)&1)<<6)|(((t>>7)&1)<<7)|(((t>>8)&1)<<12);
      const int pj = physx(jb);
      #pragma unroll
      for (int c = 0; c < 16; ++c) a[c] = lds[pj ^ pdep4<8,9,10,11>(c)];
      gate_pk<1>(a, gp(gates,0,8));
      const unsigned gb = (unsigned)(jb | (f << 13)) + stBase;
      #pragma unroll
      for (int c = 0; c < 16; ++c) st[gb + (unsigned)dep4<8,9,10,11>(c)] = pack_bf2(a[c]);
    }
  }
  else if (PASS == 2){
    // ---- R1: t->gg0-7,13; c->gg14-17; L1 gates gg14-17 ----
    {
      const unsigned gb = stBase + (unsigned)((t&255) | (((t>>8)&1)<<13) | (f<<8));
      #pragma unroll
      for (int c = 0; c < 16; ++c) a[c] = unpack_bf2(st[gb + ((unsigned)c<<14)]);
      gate_pk<1>(a, gp(gates,0,14));
      gate_pk<2>(a, gp(gates,0,15));
      gate_pk<4>(a, gp(gates,0,16));
      gate_pk<8>(a, gp(gates,0,17));
      const int pj = physx(t);
      #pragma unroll
      for (int c = 0; c < 16; ++c) lds[pj ^ pdep4<9,10,11,12>(c)] = a[c];
    }
    __syncthreads();
    // ---- R2: c->j{8,2,3,4}, t0,t1->j10,j11; L1 gg13, sign1, L2 gg13,2,3,4 + dpp gg15,16 ----
    {
      const int jb = ((t&1)<<10)|(((t>>1)&1)<<11)|(((t>>2)&1)<<0)|(((t>>3)&1)<<1)
                   | (((t>>4)&1)<<5)|(((t>>5)&1)<<6)|(((t>>6)&1)<<7)|(((t>>7)&1)<<9)|(((t>>8)&1)<<12);
      const int pj = physx(jb);
      #pragma unroll
      for (int c = 0; c < 16; ++c) a[c] = lds[pj ^ pdep4<8,2,3,4>(c)];
      gate_pk<1>(a, gp(gates,0,13));            // last L1
      const unsigned gsb = (unsigned)((jb&255) | ((jb>>8)<<13) | (f<<8));
      #pragma unroll
      for (int c = 0; c < 16; ++c)              // sign1
        sgn(a[c], gsb | (unsigned)(((c&1)<<13)|(((c>>1)&1)<<2)|(((c>>2)&1)<<3)|(((c>>3)&1)<<4)));
      gate_pk<1>(a, gp(gates,1,13));
      gate_pk<2>(a, gp(gates,1,2));
      gate_pk<4>(a, gp(gates,1,3));
      gate_pk<8>(a, gp(gates,1,4));
      gate_lane_pk<0xB1>(a, gp(gates,1,15), s1);
      gate_lane_pk<0x4E>(a, gp(gates,1,16), s2);
      #pragma unroll
      for (int c = 0; c < 16; ++c) lds[pj ^ pdep4<8,2,3,4>(c)] = a[c];
    }
    __syncthreads();
    // ---- R3: t0-5->j0-5, c->j{6,7,9,12}; L2 gg6,7,14,17 + dpp gg0,1; store ----
    {
      const int jb = (t&63)|(((t>>6)&1)<<8)|(((t>>7)&1)<<10)|(((t>>8)&1)<<11);
      const int pj = physx(jb);
      #pragma unroll
      for (int c = 0; c < 16; ++c) a[c] = lds[pj ^ pdep4<6,7,9,12>(c)];
      gate_pk<1>(a, gp(gates,1,6));
      gate_pk<2>(a, gp(gates,1,7));
      gate_pk<4>(a, gp(gates,1,14));
      gate_pk<8>(a, gp(gates,1,17));
      gate_lane_pk<0xB1>(a, gp(gates,1,0), s1);
      gate_lane_pk<0x4E>(a, gp(gates,1,1), s2);
      #pragma unroll
      for (int c = 0; c < 16; ++c){
        const int j = jb | dep4<6,7,9,12>(c);
        st[stBase + (unsigned)((j&255) | ((j>>8)<<13) | (f<<8))] = pack_bf2(a[c]);
      }
    }
  }
  else if (PASS == 3){
    const unsigned fp3 = (unsigned)(((f&3)<<6) | (((f>>2)&7)<<14));
    // ---- R1: t->gg0-5,8-10; c->gg11,12,13,17; L2 gates gg11,12 ----
    {
      const unsigned gb = stBase + (unsigned)((t&63) | (((t>>6)&7)<<8)) + fp3;
      #pragma unroll
      for (int c = 0; c < 16; ++c)
        a[c] = unpack_bf2(st[gb + (unsigned)(((c&7)<<11) | (((c>>3)&1)<<17))]);
      gate_pk<1>(a, gp(gates,1,11));
      gate_pk<2>(a, gp(gates,1,12));
      const int pj = physx(t);
      #pragma unroll
      for (int c = 0; c < 16; ++c) lds[pj ^ pdep4<9,10,11,12>(c)] = a[c];
    }
    __syncthreads();
    // ---- R2: c->j{5,6,7,8}, t0,t1->j11,j12; L2 gg5,8,9,10; sign2; L3 gg5,8,9,10 + dpp gg13,17 ----
    {
      const int jb = ((t&1)<<11)|(((t>>1)&1)<<12)|(((t>>2)&1)<<1)|(((t>>3)&1)<<2)
                   | (((t>>4)&1)<<0)|(((t>>5)&1)<<3)|(((t>>6)&1)<<4)|(((t>>7)&1)<<9)|(((t>>8)&1)<<10);
      const int pj = physx(jb);
      #pragma unroll
      for (int c = 0; c < 16; ++c) a[c] = lds[pj ^ pdep4<5,6,7,8>(c)];
      gate_pk<1>(a, gp(gates,1,5));
      gate_pk<2>(a, gp(gates,1,8));
      gate_pk<4>(a, gp(gates,1,9));
      gate_pk<8>(a, gp(gates,1,10));            // L2 complete
      const unsigned gsb = (unsigned)((jb&63) | (((jb>>6)&63)<<8) | (((jb>>12)&1)<<17)) | fp3;
      #pragma unroll
      for (int c = 0; c < 16; ++c)              // sign2
        sgn(a[c], gsb | (unsigned)(((c&1)<<5)|(((c>>1)&1)<<8)|(((c>>2)&1)<<9)|(((c>>3)&1)<<10)));
      gate_pk<1>(a, gp(gates,2,5));
      gate_pk<2>(a, gp(gates,2,8));
      gate_pk<4>(a, gp(gates,2,9));
      gate_pk<8>(a, gp(gates,2,10));
      gate_lane_pk<0xB1>(a, gp(gates,2,13), s1);
      gate_lane_pk<0x4E>(a, gp(gates,2,17), s2);
      #pragma unroll
      for (int c = 0; c < 16; ++c) lds[pj ^ pdep4<5,6,7,8>(c)] = a[c];
    }
    __syncthreads();
    // ---- R3: t0-5->j0-5, c->j{9,10,8,11}; L3 gg11,12 + dpp gg0,1; store ----
    {
      const int jb = (t&63)|(((t>>6)&1)<<6)|(((t>>7)&1)<<7)|(((t>>8)&1)<<12);
      const int pj = physx(jb);
      #pragma unroll
      for (int c = 0; c < 16; ++c) a[c] = lds[pj ^ pdep4<9,10,8,11>(c)];
      gate_pk<1>(a, gp(gates,2,11));
      gate_pk<2>(a, gp(gates,2,12));
      gate_lane_pk<0xB1>(a, gp(gates,2,0), s1);
      gate_lane_pk<0x4E>(a, gp(gates,2,1), s2);
      #pragma unroll
      for (int c = 0; c < 16; ++c){
        const int j = jb | dep4<9,10,8,11>(c);
        st[stBase + ((unsigned)((j&63) | (((j>>6)&63)<<8) | (((j>>12)&1)<<17)) | fp3)] = pack_bf2(a[c]);
      }
    }
  }
  else {
    const unsigned fp4 = (unsigned)(((f&15)<<10) | (((f>>4)&1)<<17));
    // ---- R1: t->gg0-8; c->gg9,14,15,16; L3 gates gg14,15,16 ----
    {
      const unsigned gb = stBase + (unsigned)t + fp4;
      #pragma unroll
      for (int c = 0; c < 16; ++c)
        a[c] = unpack_bf2(st[gb + (unsigned)(((c&1)<<9) | (((c>>1)&7)<<14))]);
      gate_pk<2>(a, gp(gates,2,14));
      gate_pk<4>(a, gp(gates,2,15));
      gate_pk<8>(a, gp(gates,2,16));
      const int pj = physx(t);
      #pragma unroll
      for (int c = 0; c < 16; ++c) lds[pj ^ pdep4<9,10,11,12>(c)] = a[c];
    }
    __syncthreads();
    // ---- R2: c->j{2,3,4,6}, t0->j7; L3 gg2,3,4,6 + dpp gg7; head reduce ----
    {
      const int jb = ((t&1)<<7)|(((t>>1)&1)<<5)|(((t>>2)&1)<<0)|(((t>>3)&1)<<10)
                   | (((t>>4)&1)<<1)|(((t>>5)&1)<<8)|(((t>>6)&1)<<9)|(((t>>7)&1)<<11)|(((t>>8)&1)<<12);
      const int pj = physx(jb);
      #pragma unroll
      for (int c = 0; c < 16; ++c) a[c] = lds[pj ^ pdep4<2,3,4,6>(c)];
      gate_pk<1>(a, gp(gates,2,2));
      gate_pk<2>(a, gp(gates,2,3));
      gate_pk<4>(a, gp(gates,2,4));
      gate_pk<8>(a, gp(gates,2,6));
      gate_lane_pk<0xB1>(a, gp(gates,2,7), s1);
      // fused head: coef(gg) = sum_w hw[w]*(1-2*bit_{17-w}(gg))
      const unsigned gg0 = (unsigned)((jb&1023) | (((jb>>10)&7)<<14)) | fp4;
      float cb = 0.f;
      #pragma unroll
      for (int k = 0; k < 18; ++k){
        const float hw = head_w[17-k];
        cb += ((gg0 >> k) & 1) ? -hw : hw;
      }
      // c bits -> gg{2,3,4,6} -> wires {15,14,13,11}
      const float d0 = -2.f*head_w[15], d1 = -2.f*head_w[14];
      const float d2 = -2.f*head_w[13], d3 = -2.f*head_w[11];
      float acc = 0.f;
      #pragma unroll
      for (int c = 0; c < 16; ++c){
        float coef = cb;
        if (c & 1) coef += d0;
        if (c & 2) coef += d1;
        if (c & 4) coef += d2;
        if (c & 8) coef += d3;
        acc += coef * (a[c].x*a[c].x + a[c].y*a[c].y);
      }
      __syncthreads();   // all LDS reads done; reuse LDS for reduction
      #pragma unroll
      for (int off = 32; off; off >>= 1) acc += __shfl_down(acc, off);
      float* red = reinterpret_cast<float*>(lds);
      if ((t & 63) == 0) red[t >> 6] = acc;
      __syncthreads();
      if (t == 0){
        float s = 0.f;
        #pragma unroll
        for (int i = 0; i < 8; ++i) s += red[i];
        partials[bg * 32 + f] = s;
      }
    }
  }
}

__global__ void qprep(const float* __restrict__ params, float* __restrict__ gates){
  const int tid = threadIdx.x;
  if (tid < 54){
    const float xx = params[tid*3+0]*0.5f, yy = params[tid*3+1]*0.5f, zz = params[tid*3+2]*0.5f;
    float sx,cx,sy,cy,sz,cz;
    sincosf(xx,&sx,&cx); sincosf(yy,&sy,&cy); sincosf(zz,&sz,&cz);
    float* g = gates + tid*4;
    g[0] =  cz*cy*cx + sz*sy*sx;   // a_r (u00)
    g[1] =  cz*sy*sx - sz*cy*cx;   // a_i
    g[2] = -cz*sy*cx - sz*cy*sx;   // b_r (u01)
    g[3] =  sz*sy*cx - cz*cy*sx;   // b_i
  }
}

__global__ void qfinal(const float* __restrict__ partials, const float* __restrict__ head_b,
                       float* __restrict__ out, int B){
  const int b = threadIdx.x + blockIdx.x * blockDim.x;
  if (b < B){
    float s = head_b[0];
    #pragma unroll
    for (int i = 0; i < 32; ++i) s += partials[b*32 + i];
    out[b] = s;
  }
}

extern "C" void kernel_launch(void* const* d_in, const int* in_sizes, int n_in,
                              void* d_out, int out_size, void* d_ws, size_t ws_size,
                              hipStream_t stream){
  const float* sr     = (const float*)d_in[0];
  const float* si     = (const float*)d_in[1];
  const float* params = (const float*)d_in[2];
  const float* head_w = (const float*)d_in[3];
  const float* head_b = (const float*)d_in[4];
  float* out = (float*)d_out;
  const int B = in_sizes[0] >> DBITS;   // 128

  float*    gates    = (float*)d_ws;                        // 54*4 floats
  float*    partials = (float*)((char*)d_ws + 4096);        // B*32 floats
  unsigned* st       = (unsigned*)((char*)d_ws + 24576);    // bf16-packed state chunk

  size_t stBytes = ws_size > 24576 ? ws_size - 24576 : 0;
  int maxChunk = (int)(stBytes / ((size_t)(1 << DBITS) * 4));
  if (maxChunk > B) maxChunk = B;
  if (maxChunk < 1) maxChunk = 1;

  qprep<<<dim3(1), dim3(64), 0, stream>>>(params, gates);

  for (int b0 = 0; b0 < B; b0 += maxChunk){
    const int c = (B - b0 < maxChunk) ? (B - b0) : maxChunk;
    dim3 grid(c * 32), blk(512);
    qpass<1><<<grid, blk, 0, stream>>>(sr, si, st, gates, head_w, partials, b0);
    qpass<2><<<grid, blk, 0, stream>>>(sr, si, st, gates, head_w, partials, b0);
    qpass<3><<<grid, blk, 0, stream>>>(sr, si, st, gates, head_w, partials, b0);
    qpass<4><<<grid, blk, 0, stream>>>(sr, si, st, gates, head_w, partials, b0);
  }
  qfinal<<<dim3(1), dim3(128), 0, stream>>>(partials, head_b, out, B);
}